// Round 3
// baseline (3130.759 us; speedup 1.0000x reference)
//
#include <hip/hip_runtime.h>
#include <hip/hip_bf16.h>

// BiLSTM-CRF NLL on MI355X.
// Pipeline: K0 (W_ih transpose + bias fold) -> K1 (gather + input GEMM)
//        -> K2 (sequential LSTM, 1 CU per direction, split-K + quad shuffle)
//        -> K3 (tag projection)
//        -> K4a (parallel CRF chunk products, log-semiring) -> K4b (apply + gold).

#define SLEN 4096
#define EMBD 256
#define HD   128
#define G4   512          // 4*H
#define TT   12
#define STARTT 10
#define ENDT   11
#define NEGV  -1000000.0f
#define CLEN   16
#define NCHUNK 256        // SLEN / CLEN

// ws layout (float offsets)
#define OFF_WT    0u          // 2 * 256*512   = 262144
#define OFF_BSUM  262144u     // 2 * 512       = 1024
#define OFF_PRE   263168u     // 2 * 4096*512  = 4194304
#define OFF_H     4457472u    // 2 * 4096*128  = 1048576
#define OFF_FEATS 5506048u    // 4096*12       = 49152
#define OFF_CMAT  5555200u    // 256*144       = 36864
// total = 5592064 floats ~= 22.4 MB

__device__ __forceinline__ float sig_fast(float x) {
    // 1/(1+e^-x); rcp(inf)=0 so saturates cleanly, no NaN.
    return __builtin_amdgcn_rcpf(1.0f + __expf(-x));
}
__device__ __forceinline__ float tanh_fast(float x) {
    // tanh(x) = 2*sigmoid(2x) - 1
    return fmaf(2.0f, __builtin_amdgcn_rcpf(1.0f + __expf(-2.0f * x)), -1.0f);
}

// ---------------- K0: transpose W_ih -> WT[k][j], fold biases ----------------
__global__ __launch_bounds__(256) void k0_prep(
    const float* __restrict__ Wih_f, const float* __restrict__ Wih_b,
    const float* __restrict__ bih_f, const float* __restrict__ bhh_f,
    const float* __restrict__ bih_b, const float* __restrict__ bhh_b,
    float* __restrict__ ws)
{
    const int dir = blockIdx.y;
    const float* Wih = dir ? Wih_b : Wih_f;
    float* WT = ws + OFF_WT + (unsigned)dir * 131072u;
    const int gid = blockIdx.x * 256 + threadIdx.x;       // grid.x = 32 -> 8192 threads
#pragma unroll
    for (int m = 0; m < 16; ++m) {
        int linear = m * 8192 + gid;                      // 0..131071
        int j = linear >> 8;
        int k = linear & 255;
        WT[k * G4 + j] = Wih[j * EMBD + k];
    }
    if (gid < G4) {
        const float* bi = dir ? bih_b : bih_f;
        const float* bh = dir ? bhh_b : bhh_f;
        ws[OFF_BSUM + (unsigned)dir * 512u + gid] = bi[gid] + bh[gid];
    }
}

// ---------------- K1: pre[t][j] = sum_k WT[k][j]*x[t][k] + bsum[j] ----------
__global__ __launch_bounds__(256) void k1_pre(
    const int* __restrict__ sentence, const float* __restrict__ emb,
    float* __restrict__ ws)
{
    const int dir = blockIdx.y;
    const int tbase = blockIdx.x * 16;
    const float* WT   = ws + OFF_WT   + (unsigned)dir * 131072u;
    const float* bsum = ws + OFF_BSUM + (unsigned)dir * 512u;
    float* pre        = ws + OFF_PRE  + (unsigned)dir * 2097152u;

    __shared__ float xs[16][EMBD];
    const int tid = threadIdx.x;

    for (int m = 0; m < 16; ++m) {
        int t = tbase + m;
        int row = dir ? (SLEN - 1 - t) : t;
        int sid = sentence[row];
        xs[m][tid] = emb[(size_t)sid * EMBD + tid];
    }
    __syncthreads();

    const int jj = tid & 127;
    const int th = tid >> 7;          // 0/1: which 8-timestep half

    float acc[8][4];
#pragma unroll
    for (int a = 0; a < 8; ++a)
#pragma unroll
        for (int b = 0; b < 4; ++b) acc[a][b] = 0.0f;

#pragma unroll 2
    for (int k = 0; k < EMBD; ++k) {
        const float* wr = WT + k * G4 + jj;
        float w0 = wr[0], w1 = wr[128], w2 = wr[256], w3 = wr[384];
#pragma unroll
        for (int t8 = 0; t8 < 8; ++t8) {
            float xv = xs[th * 8 + t8][k];     // wave-uniform broadcast
            acc[t8][0] = fmaf(xv, w0, acc[t8][0]);
            acc[t8][1] = fmaf(xv, w1, acc[t8][1]);
            acc[t8][2] = fmaf(xv, w2, acc[t8][2]);
            acc[t8][3] = fmaf(xv, w3, acc[t8][3]);
        }
    }

    float b0 = bsum[jj], b1 = bsum[jj + 128], b2 = bsum[jj + 256], b3 = bsum[jj + 384];
#pragma unroll
    for (int t8 = 0; t8 < 8; ++t8) {
        int t = tbase + th * 8 + t8;
        float* pr = pre + (size_t)t * G4 + jj;
        pr[0]   = acc[t8][0] + b0;
        pr[128] = acc[t8][1] + b1;
        pr[256] = acc[t8][2] + b2;
        pr[384] = acc[t8][3] + b3;
    }
}

// ---------------- K2: sequential LSTM, one block per direction --------------
// 512 threads: (j,q) = (tid>>2, tid&3). Thread computes all-4-gate partial
// dots over k-quarter q (128 fma), quad shuffle-reduce, redundant epilogue,
// q==0 publishes h. ONE barrier per step; h double-buffered in LDS.
// h layout swizzled so per-(q,m) ds_read_b128 quads are distinct + broadcast.
// NOTE: __launch_bounds__(512) ONLY — adding min-waves=2 caps VGPR at 128
// and spills the 128-float weight array into the serial loop.
__global__ __launch_bounds__(512) void k2_lstm(
    const float* __restrict__ Whh_f, const float* __restrict__ Whh_b,
    const float* __restrict__ h0, const float* __restrict__ c0,
    float* __restrict__ ws)
{
    const int dir = blockIdx.x;
    const float* Whh = dir ? Whh_b : Whh_f;
    const float* pre = ws + OFF_PRE + (unsigned)dir * 2097152u;
    float* hout      = ws + OFF_H   + (unsigned)dir * 524288u;

    __shared__ __align__(16) float hbuf[2][HD];   // double-buffered, swizzled

    const int tid = threadIdx.x;
    const int j = tid >> 2;           // 0..127: output element
    const int q = tid & 3;            // k-quarter

    // swizzled float index for h element jj: 16*((jj>>2)&7) + 4*(jj>>5) + (jj&3)
    const int wr_idx = 16 * ((j >> 2) & 7) + 4 * (j >> 5) + (j & 3);

    // weights: w[g][kk] = Whh[(g*128+j)][q*32+kk]   (statically indexed -> VGPRs)
    float w[4][32];
#pragma unroll
    for (int g = 0; g < 4; ++g) {
        const float* wrow = Whh + (size_t)(g * HD + j) * HD + q * 32;
#pragma unroll
        for (int m = 0; m < 8; ++m) {
            float4 wv = ((const float4*)wrow)[m];
            w[g][4*m+0] = wv.x; w[g][4*m+1] = wv.y;
            w[g][4*m+2] = wv.z; w[g][4*m+3] = wv.w;
        }
    }

    float c = c0[dir * HD + j];       // replicated across the 4 q-partners
    if (q == 0) hbuf[0][wr_idx] = h0[dir * HD + j];
    __syncthreads();

    float pcur[4], pnext[4];
#pragma unroll
    for (int g = 0; g < 4; ++g) pcur[g] = pre[g * HD + j];

    for (int s = 0; s < SLEN; ++s) {
        const int cur = s & 1;
        const int snext = (s + 1 < SLEN) ? s + 1 : SLEN - 1;
        const float* prn = pre + (size_t)snext * G4;
#pragma unroll
        for (int g = 0; g < 4; ++g) pnext[g] = prn[g * HD + j];

        // read this thread's k-quarter of h (swizzled: float4 slot 4m+q)
        float4 hq[8];
        const float4* hb4 = (const float4*)hbuf[cur];
#pragma unroll
        for (int m = 0; m < 8; ++m) hq[m] = hb4[4 * m + q];

        float a0 = 0.f, a1 = 0.f, a2 = 0.f, a3 = 0.f;
#pragma unroll
        for (int m = 0; m < 8; ++m) {
            float4 hv = hq[m];
            a0 = fmaf(w[0][4*m+0], hv.x, a0); a0 = fmaf(w[0][4*m+1], hv.y, a0);
            a0 = fmaf(w[0][4*m+2], hv.z, a0); a0 = fmaf(w[0][4*m+3], hv.w, a0);
            a1 = fmaf(w[1][4*m+0], hv.x, a1); a1 = fmaf(w[1][4*m+1], hv.y, a1);
            a1 = fmaf(w[1][4*m+2], hv.z, a1); a1 = fmaf(w[1][4*m+3], hv.w, a1);
            a2 = fmaf(w[2][4*m+0], hv.x, a2); a2 = fmaf(w[2][4*m+1], hv.y, a2);
            a2 = fmaf(w[2][4*m+2], hv.z, a2); a2 = fmaf(w[2][4*m+3], hv.w, a2);
            a3 = fmaf(w[3][4*m+0], hv.x, a3); a3 = fmaf(w[3][4*m+1], hv.y, a3);
            a3 = fmaf(w[3][4*m+2], hv.z, a3); a3 = fmaf(w[3][4*m+3], hv.w, a3);
        }

        // quad butterfly over q (lanes differ in bits 0,1 -> in-wave)
        a0 += __shfl_xor(a0, 1); a0 += __shfl_xor(a0, 2);
        a1 += __shfl_xor(a1, 1); a1 += __shfl_xor(a1, 2);
        a2 += __shfl_xor(a2, 1); a2 += __shfl_xor(a2, 2);
        a3 += __shfl_xor(a3, 1); a3 += __shfl_xor(a3, 2);

        // redundant epilogue on all 4 partners (identical -> deterministic)
        float iv = sig_fast(a0 + pcur[0]);
        float fv = sig_fast(a1 + pcur[1]);
        float gv = tanh_fast(a2 + pcur[2]);
        float ov = sig_fast(a3 + pcur[3]);
        c = fmaf(fv, c, iv * gv);
        float h = ov * tanh_fast(c);

        if (q == 0) {
            hbuf[cur ^ 1][wr_idx] = h;
            int tstore = dir ? (SLEN - 1 - s) : s;
            hout[(size_t)tstore * HD + j] = h;
        }
        __syncthreads();              // publishes h(s+1); orders next-step reads

#pragma unroll
        for (int g = 0; g < 4; ++g) pcur[g] = pnext[g];
    }
}

// ---------------- K3: feats[t] = [h_f h_b] @ W_tag^T + b_tag ----------------
__global__ __launch_bounds__(256) void k3_feats(
    const float* __restrict__ Wtag, const float* __restrict__ btag,
    float* __restrict__ ws)
{
    const float* hf = ws + OFF_H;
    const float* hb = ws + OFF_H + 524288u;
    float* feats    = ws + OFF_FEATS;

    const int t = blockIdx.x * 4 + (threadIdx.x >> 6);
    const int l = threadIdx.x & 63;

    float x0 = hf[(size_t)t * HD + l];
    float x1 = hf[(size_t)t * HD + 64 + l];
    float x2 = hb[(size_t)t * HD + l];
    float x3 = hb[(size_t)t * HD + 64 + l];

#pragma unroll
    for (int n = 0; n < TT; ++n) {
        const float* wr = Wtag + n * 256;
        float p = wr[l] * x0 + wr[64 + l] * x1 + wr[128 + l] * x2 + wr[192 + l] * x3;
#pragma unroll
        for (int off = 32; off; off >>= 1) p += __shfl_xor(p, off);
        if (l == 0) feats[t * TT + n] = p + btag[n];
    }
}

// ---------------- K4a: per-chunk log-semiring matrix product ----------------
// Chunk b folds step matrices M_t (t = 16b .. 16b+15) into P_b[12][12]:
//   M_t[n,p] = trans[n,p] + f_t[n];  P <- M_t o P, (A o B)[n,p] = LSE_k(A[n,k]+B[k,p])
// 144 active threads, one (n,p) output each; P double-buffered in LDS.
__global__ __launch_bounds__(192) void k4a_chunk(
    const float* __restrict__ trans, float* __restrict__ ws)
{
    const int b = blockIdx.x;
    const float* feats = ws + OFF_FEATS;
    float* cmat = ws + OFF_CMAT + (unsigned)b * 144u;

    __shared__ float P[2][TT][16];
    __shared__ float fbuf[CLEN][TT];
    __shared__ float tl[TT * TT];

    const int tid = threadIdx.x;
    fbuf[tid / TT][tid % TT] = feats[(size_t)b * CLEN * TT + tid];  // 192 = 16*12
    if (tid < TT * TT) tl[tid] = trans[tid];
    __syncthreads();

    const int n = tid / TT;           // valid for tid < 144
    const int p = tid % TT;
    float tr[TT];
    if (tid < 144) {
#pragma unroll
        for (int k = 0; k < TT; ++k) tr[k] = tl[n * TT + k];
        P[0][n][p] = tr[p] + fbuf[0][n];          // P = M_{16b}
    }
    __syncthreads();

    int cur = 0;
#pragma unroll
    for (int t = 1; t < CLEN; ++t) {
        if (tid < 144) {
            float a[TT];
#pragma unroll
            for (int k = 0; k < TT; ++k) a[k] = tr[k] + P[cur][k][p];
            float m = a[0];
#pragma unroll
            for (int k = 1; k < TT; ++k) m = fmaxf(m, a[k]);
            float s = 0.f;
#pragma unroll
            for (int k = 0; k < TT; ++k) s += __expf(a[k] - m);   // s >= 1 (max-shift)
            P[cur ^ 1][n][p] = fbuf[t][n] + m + __logf(s);
        }
        __syncthreads();
        cur ^= 1;
    }
    if (tid < 144) cmat[tid] = P[cur][n][p];      // row-major [n][p]
}

// ---------------- K4b: gold score + sequential chunk apply + final LSE ------
__global__ __launch_bounds__(256) void k4b_final(
    const int* __restrict__ gold_tags, const float* __restrict__ trans,
    float* __restrict__ ws, float* __restrict__ out)
{
    const float* feats = ws + OFF_FEATS;
    const float* cmat  = ws + OFF_CMAT;
    __shared__ float red[256];
    __shared__ float gold_s;
    const int tid = threadIdx.x;

    // gold path score
    float local = 0.0f;
    for (int i = tid; i < SLEN; i += 256) {
        int curt = gold_tags[i];
        int prev = (i == 0) ? STARTT : gold_tags[i - 1];
        local += trans[curt * TT + prev] + feats[i * TT + curt];
    }
    red[tid] = local;
    __syncthreads();
    for (int sft = 128; sft; sft >>= 1) {
        if (tid < sft) red[tid] += red[tid + sft];
        __syncthreads();
    }
    if (tid == 0) gold_s = red[0] + trans[ENDT * TT + gold_tags[SLEN - 1]];
    __syncthreads();
    if (tid >= 64) return;            // wave 0 continues barrier-free

    const int lane = tid;
    const int n = (lane < TT) ? lane : 0;

    float alpha = (lane == STARTT) ? 0.0f : NEGV;
    float cr[TT], cn[TT];
#pragma unroll
    for (int p = 0; p < TT; ++p) cr[p] = cmat[n * TT + p];   // chunk 0 row n

    for (int b = 0; b < NCHUNK; ++b) {
        const float* nxt = cmat + (size_t)((b + 1 < NCHUNK) ? b + 1 : b) * 144u;
#pragma unroll
        for (int p = 0; p < TT; ++p) cn[p] = nxt[n * TT + p]; // prefetch next chunk

        float a[TT];
#pragma unroll
        for (int p = 0; p < TT; ++p) a[p] = __shfl(alpha, p) + cr[p];
        float m = a[0];
#pragma unroll
        for (int p = 1; p < TT; ++p) m = fmaxf(m, a[p]);
        float s = 0.f;
#pragma unroll
        for (int p = 0; p < TT; ++p) s += __expf(a[p] - m);
        float na = m + __logf(s);
        alpha = (lane < TT) ? na : NEGV;
#pragma unroll
        for (int p = 0; p < TT; ++p) cr[p] = cn[p];
    }

    // forward_score = LSE(alpha + trans[END]) ; out = forward - gold
    float v = (lane < TT) ? alpha + trans[ENDT * TT + lane] : -1e30f;
    float mm = v;
#pragma unroll
    for (int off = 32; off; off >>= 1) mm = fmaxf(mm, __shfl_xor(mm, off));
    float ee = (lane < TT) ? __expf(v - mm) : 0.0f;
#pragma unroll
    for (int off = 32; off; off >>= 1) ee += __shfl_xor(ee, off);
    if (lane == 0) out[0] = mm + __logf(ee) - gold_s;
}

// ---------------------------------------------------------------------------
extern "C" void kernel_launch(void* const* d_in, const int* in_sizes, int n_in,
                              void* d_out, int out_size, void* d_ws, size_t ws_size,
                              hipStream_t stream)
{
    const int*   sentence = (const int*)  d_in[0];
    const int*   gold     = (const int*)  d_in[1];
    const float* emb      = (const float*)d_in[2];
    const float* Wih_f    = (const float*)d_in[3];
    const float* Whh_f    = (const float*)d_in[4];
    const float* bih_f    = (const float*)d_in[5];
    const float* bhh_f    = (const float*)d_in[6];
    const float* Wih_b    = (const float*)d_in[7];
    const float* Whh_b    = (const float*)d_in[8];
    const float* bih_b    = (const float*)d_in[9];
    const float* bhh_b    = (const float*)d_in[10];
    const float* h0       = (const float*)d_in[11];
    const float* c0       = (const float*)d_in[12];
    const float* Wtag     = (const float*)d_in[13];
    const float* btag     = (const float*)d_in[14];
    const float* trans    = (const float*)d_in[15];
    float* out = (float*)d_out;
    float* ws  = (float*)d_ws;

    k0_prep  <<<dim3(32, 2),  256, 0, stream>>>(Wih_f, Wih_b, bih_f, bhh_f, bih_b, bhh_b, ws);
    k1_pre   <<<dim3(256, 2), 256, 0, stream>>>(sentence, emb, ws);
    k2_lstm  <<<2,            512, 0, stream>>>(Whh_f, Whh_b, h0, c0, ws);
    k3_feats <<<1024,         256, 0, stream>>>(Wtag, btag, ws);
    k4a_chunk<<<NCHUNK,       192, 0, stream>>>(trans, ws);
    k4b_final<<<1,            256, 0, stream>>>(gold, trans, ws, out);
}

// Round 7
// 2820.361 us; speedup vs baseline: 1.1101x; 1.1101x over previous
//
#include <hip/hip_runtime.h>
#include <hip/hip_bf16.h>

// BiLSTM-CRF NLL on MI355X.
// Pipeline: K0 (W_ih transpose + bias fold) -> K1 (gather + input GEMM)
//        -> K2 (sequential LSTM, 1 CU per direction, split-K + DPP quad reduce)
//        -> K3 (tag projection)
//        -> K4a (parallel CRF chunk products, log-semiring) -> K4b (apply + gold).

#define SLEN 4096
#define EMBD 256
#define HD   128
#define G4   512          // 4*H
#define TT   12
#define STARTT 10
#define ENDT   11
#define NEGV  -1000000.0f
#define CLEN   16
#define NCHUNK 256        // SLEN / CLEN

// ws layout (float offsets)
#define OFF_WT    0u          // 2 * 256*512   = 262144
#define OFF_BSUM  262144u     // 2 * 512       = 1024
#define OFF_PRE   263168u     // 2 * 4096*512  = 4194304
#define OFF_H     4457472u    // 2 * 4096*128  = 1048576
#define OFF_FEATS 5506048u    // 4096*12       = 49152
#define OFF_CMAT  5555200u    // 256*144       = 36864
// total = 5592064 floats ~= 22.4 MB

__device__ __forceinline__ float sig_fast(float x) {
    // 1/(1+e^-x); rcp(inf)=0 so saturates cleanly, no NaN.
    return __builtin_amdgcn_rcpf(1.0f + __expf(-x));
}
__device__ __forceinline__ float tanh_fast(float x) {
    // tanh(x) = 2*sigmoid(2x) - 1
    return fmaf(2.0f, __builtin_amdgcn_rcpf(1.0f + __expf(-2.0f * x)), -1.0f);
}

// quad (lanes l^1, l^2) butterfly sum via DPP — ~8 cyc/round vs ~40 for
// ds_bpermute-based __shfl_xor. quad_perm[1,0,3,2]=0xB1, [2,3,0,1]=0x4E.
__device__ __forceinline__ float quad_sum_dpp(float x) {
    x += __int_as_float(__builtin_amdgcn_update_dpp(0, __float_as_int(x), 0xB1, 0xF, 0xF, true));
    x += __int_as_float(__builtin_amdgcn_update_dpp(0, __float_as_int(x), 0x4E, 0xF, 0xF, true));
    return x;
}

// ---------------- K0: transpose W_ih -> WT[k][j], fold biases ----------------
__global__ __launch_bounds__(256) void k0_prep(
    const float* __restrict__ Wih_f, const float* __restrict__ Wih_b,
    const float* __restrict__ bih_f, const float* __restrict__ bhh_f,
    const float* __restrict__ bih_b, const float* __restrict__ bhh_b,
    float* __restrict__ ws)
{
    const int dir = blockIdx.y;
    const float* Wih = dir ? Wih_b : Wih_f;
    float* WT = ws + OFF_WT + (unsigned)dir * 131072u;
    const int gid = blockIdx.x * 256 + threadIdx.x;       // grid.x = 32 -> 8192 threads
#pragma unroll
    for (int m = 0; m < 16; ++m) {
        int linear = m * 8192 + gid;                      // 0..131071
        int j = linear >> 8;
        int k = linear & 255;
        WT[k * G4 + j] = Wih[j * EMBD + k];
    }
    if (gid < G4) {
        const float* bi = dir ? bih_b : bih_f;
        const float* bh = dir ? bhh_b : bhh_f;
        ws[OFF_BSUM + (unsigned)dir * 512u + gid] = bi[gid] + bh[gid];
    }
}

// ---------------- K1: pre[t][j] = sum_k WT[k][j]*x[t][k] + bsum[j] ----------
__global__ __launch_bounds__(256) void k1_pre(
    const int* __restrict__ sentence, const float* __restrict__ emb,
    float* __restrict__ ws)
{
    const int dir = blockIdx.y;
    const int tbase = blockIdx.x * 16;
    const float* WT   = ws + OFF_WT   + (unsigned)dir * 131072u;
    const float* bsum = ws + OFF_BSUM + (unsigned)dir * 512u;
    float* pre        = ws + OFF_PRE  + (unsigned)dir * 2097152u;

    __shared__ float xs[16][EMBD];
    const int tid = threadIdx.x;

    for (int m = 0; m < 16; ++m) {
        int t = tbase + m;
        int row = dir ? (SLEN - 1 - t) : t;
        int sid = sentence[row];
        xs[m][tid] = emb[(size_t)sid * EMBD + tid];
    }
    __syncthreads();

    const int jj = tid & 127;
    const int th = tid >> 7;          // 0/1: which 8-timestep half

    float acc[8][4];
#pragma unroll
    for (int a = 0; a < 8; ++a)
#pragma unroll
        for (int b = 0; b < 4; ++b) acc[a][b] = 0.0f;

#pragma unroll 2
    for (int k = 0; k < EMBD; ++k) {
        const float* wr = WT + k * G4 + jj;
        float w0 = wr[0], w1 = wr[128], w2 = wr[256], w3 = wr[384];
#pragma unroll
        for (int t8 = 0; t8 < 8; ++t8) {
            float xv = xs[th * 8 + t8][k];     // wave-uniform broadcast
            acc[t8][0] = fmaf(xv, w0, acc[t8][0]);
            acc[t8][1] = fmaf(xv, w1, acc[t8][1]);
            acc[t8][2] = fmaf(xv, w2, acc[t8][2]);
            acc[t8][3] = fmaf(xv, w3, acc[t8][3]);
        }
    }

    float b0 = bsum[jj], b1 = bsum[jj + 128], b2 = bsum[jj + 256], b3 = bsum[jj + 384];
#pragma unroll
    for (int t8 = 0; t8 < 8; ++t8) {
        int t = tbase + th * 8 + t8;
        float* pr = pre + (size_t)t * G4 + jj;
        pr[0]   = acc[t8][0] + b0;
        pr[128] = acc[t8][1] + b1;
        pr[256] = acc[t8][2] + b2;
        pr[384] = acc[t8][3] + b3;
    }
}

// ---------------- K2: sequential LSTM, one block per direction --------------
// 512 threads: (j,q) = (tid>>2, tid&3). Thread computes all-4-gate partial
// dots over k-quarter q (128 fma), DPP quad reduce, redundant epilogue,
// q==0 publishes h. ONE barrier per step; h double-buffered in LDS.
//
// __launch_bounds__(512, 2): for a 512-thread block, min-waves/EU=2 means
// ONE block/CU -> 256-VGPR budget, so w[4][32] (128 floats) stays in arch
// VGPRs. (Round-3 evidence: without it the heuristic picked VGPR_Count=84
// and AGPR-spilled the weights -> +128 v_accvgpr_read per step = ~2x.)
//
// hout global store is deferred one step (register-carried) so its retire
// latency drains under the NEXT step's dot, not at this step's barrier
// (compiler emits s_waitcnt vmcnt(0) before s_barrier).
__global__ __launch_bounds__(512, 2) void k2_lstm(
    const float* __restrict__ Whh_f, const float* __restrict__ Whh_b,
    const float* __restrict__ h0, const float* __restrict__ c0,
    float* __restrict__ ws)
{
    const int dir = blockIdx.x;
    const float* Whh = dir ? Whh_b : Whh_f;
    const float* pre = ws + OFF_PRE + (unsigned)dir * 2097152u;
    float* hout      = ws + OFF_H   + (unsigned)dir * 524288u;

    __shared__ __align__(16) float hbuf[2][HD];   // double-buffered, swizzled

    const int tid = threadIdx.x;
    const int j = tid >> 2;           // 0..127: output element
    const int q = tid & 3;            // k-quarter

    // swizzled float index for h element jj: 16*((jj>>2)&7) + 4*(jj>>5) + (jj&3)
    const int wr_idx = 16 * ((j >> 2) & 7) + 4 * (j >> 5) + (j & 3);

    // weights: w[g][kk] = Whh[(g*128+j)][q*32+kk]   (statically indexed -> VGPRs)
    float w[4][32];
#pragma unroll
    for (int g = 0; g < 4; ++g) {
        const float* wrow = Whh + (size_t)(g * HD + j) * HD + q * 32;
#pragma unroll
        for (int m = 0; m < 8; ++m) {
            float4 wv = ((const float4*)wrow)[m];
            w[g][4*m+0] = wv.x; w[g][4*m+1] = wv.y;
            w[g][4*m+2] = wv.z; w[g][4*m+3] = wv.w;
        }
    }

    float c = c0[dir * HD + j];       // replicated across the 4 q-partners
    if (q == 0) hbuf[0][wr_idx] = h0[dir * HD + j];
    __syncthreads();

    float pcur[4], pnext[4];
#pragma unroll
    for (int g = 0; g < 4; ++g) pcur[g] = pre[g * HD + j];

    float hcarry = 0.0f;              // h(s-1), pending global store (q==0)

    for (int s = 0; s < SLEN; ++s) {
        const int cur = s & 1;

        // store PREVIOUS step's h now: retires under this step's dot
        if (q == 0 && s > 0) {
            int tstore = dir ? (SLEN - s) : (s - 1);
            hout[(size_t)tstore * HD + j] = hcarry;
        }

        // prefetch next step's pre operands
        const int snext = (s + 1 < SLEN) ? s + 1 : SLEN - 1;
        const float* prn = pre + (size_t)snext * G4;
#pragma unroll
        for (int g = 0; g < 4; ++g) pnext[g] = prn[g * HD + j];

        // read this thread's k-quarter of h (swizzled: float4 slot 4m+q)
        float4 hq[8];
        const float4* hb4 = (const float4*)hbuf[cur];
#pragma unroll
        for (int m = 0; m < 8; ++m) hq[m] = hb4[4 * m + q];

        float a0 = 0.f, a1 = 0.f, a2 = 0.f, a3 = 0.f;
#pragma unroll
        for (int m = 0; m < 8; ++m) {
            float4 hv = hq[m];
            a0 = fmaf(w[0][4*m+0], hv.x, a0); a0 = fmaf(w[0][4*m+1], hv.y, a0);
            a0 = fmaf(w[0][4*m+2], hv.z, a0); a0 = fmaf(w[0][4*m+3], hv.w, a0);
            a1 = fmaf(w[1][4*m+0], hv.x, a1); a1 = fmaf(w[1][4*m+1], hv.y, a1);
            a1 = fmaf(w[1][4*m+2], hv.z, a1); a1 = fmaf(w[1][4*m+3], hv.w, a1);
            a2 = fmaf(w[2][4*m+0], hv.x, a2); a2 = fmaf(w[2][4*m+1], hv.y, a2);
            a2 = fmaf(w[2][4*m+2], hv.z, a2); a2 = fmaf(w[2][4*m+3], hv.w, a2);
            a3 = fmaf(w[3][4*m+0], hv.x, a3); a3 = fmaf(w[3][4*m+1], hv.y, a3);
            a3 = fmaf(w[3][4*m+2], hv.z, a3); a3 = fmaf(w[3][4*m+3], hv.w, a3);
        }

        // quad butterfly over q via DPP (lanes differ in bits 0,1)
        a0 = quad_sum_dpp(a0);
        a1 = quad_sum_dpp(a1);
        a2 = quad_sum_dpp(a2);
        a3 = quad_sum_dpp(a3);

        // redundant epilogue on all 4 partners (identical -> deterministic)
        float iv = sig_fast(a0 + pcur[0]);
        float fv = sig_fast(a1 + pcur[1]);
        float gv = tanh_fast(a2 + pcur[2]);
        float ov = sig_fast(a3 + pcur[3]);
        c = fmaf(fv, c, iv * gv);
        float h = ov * tanh_fast(c);

        if (q == 0) hbuf[cur ^ 1][wr_idx] = h;
        hcarry = h;
        __syncthreads();              // publishes h(s+1); orders next-step reads

#pragma unroll
        for (int g = 0; g < 4; ++g) pcur[g] = pnext[g];
    }

    if (q == 0) {                     // final step's h
        int tstore = dir ? 0 : (SLEN - 1);
        hout[(size_t)tstore * HD + j] = hcarry;
    }
}

// ---------------- K3: feats[t] = [h_f h_b] @ W_tag^T + b_tag ----------------
__global__ __launch_bounds__(256) void k3_feats(
    const float* __restrict__ Wtag, const float* __restrict__ btag,
    float* __restrict__ ws)
{
    const float* hf = ws + OFF_H;
    const float* hb = ws + OFF_H + 524288u;
    float* feats    = ws + OFF_FEATS;

    const int t = blockIdx.x * 4 + (threadIdx.x >> 6);
    const int l = threadIdx.x & 63;

    float x0 = hf[(size_t)t * HD + l];
    float x1 = hf[(size_t)t * HD + 64 + l];
    float x2 = hb[(size_t)t * HD + l];
    float x3 = hb[(size_t)t * HD + 64 + l];

#pragma unroll
    for (int n = 0; n < TT; ++n) {
        const float* wr = Wtag + n * 256;
        float p = wr[l] * x0 + wr[64 + l] * x1 + wr[128 + l] * x2 + wr[192 + l] * x3;
#pragma unroll
        for (int off = 32; off; off >>= 1) p += __shfl_xor(p, off);
        if (l == 0) feats[t * TT + n] = p + btag[n];
    }
}

// ---------------- K4a: per-chunk log-semiring matrix product ----------------
// Chunk b folds step matrices M_t (t = 16b .. 16b+15) into P_b[12][12]:
//   M_t[n,p] = trans[n,p] + f_t[n];  P <- M_t o P, (A o B)[n,p] = LSE_k(A[n,k]+B[k,p])
// 144 active threads, one (n,p) output each; P double-buffered in LDS.
__global__ __launch_bounds__(192) void k4a_chunk(
    const float* __restrict__ trans, float* __restrict__ ws)
{
    const int b = blockIdx.x;
    const float* feats = ws + OFF_FEATS;
    float* cmat = ws + OFF_CMAT + (unsigned)b * 144u;

    __shared__ float P[2][TT][16];
    __shared__ float fbuf[CLEN][TT];
    __shared__ float tl[TT * TT];

    const int tid = threadIdx.x;
    fbuf[tid / TT][tid % TT] = feats[(size_t)b * CLEN * TT + tid];  // 192 = 16*12
    if (tid < TT * TT) tl[tid] = trans[tid];
    __syncthreads();

    const int n = tid / TT;           // valid for tid < 144
    const int p = tid % TT;
    float tr[TT];
    if (tid < 144) {
#pragma unroll
        for (int k = 0; k < TT; ++k) tr[k] = tl[n * TT + k];
        P[0][n][p] = tr[p] + fbuf[0][n];          // P = M_{16b}
    }
    __syncthreads();

    int cur = 0;
#pragma unroll
    for (int t = 1; t < CLEN; ++t) {
        if (tid < 144) {
            float a[TT];
#pragma unroll
            for (int k = 0; k < TT; ++k) a[k] = tr[k] + P[cur][k][p];
            float m = a[0];
#pragma unroll
            for (int k = 1; k < TT; ++k) m = fmaxf(m, a[k]);
            float s = 0.f;
#pragma unroll
            for (int k = 0; k < TT; ++k) s += __expf(a[k] - m);   // s >= 1 (max-shift)
            P[cur ^ 1][n][p] = fbuf[t][n] + m + __logf(s);
        }
        __syncthreads();
        cur ^= 1;
    }
    if (tid < 144) cmat[tid] = P[cur][n][p];      // row-major [n][p]
}

// ---------------- K4b: gold score + sequential chunk apply + final LSE ------
__global__ __launch_bounds__(256) void k4b_final(
    const int* __restrict__ gold_tags, const float* __restrict__ trans,
    float* __restrict__ ws, float* __restrict__ out)
{
    const float* feats = ws + OFF_FEATS;
    const float* cmat  = ws + OFF_CMAT;
    __shared__ float red[256];
    __shared__ float gold_s;
    const int tid = threadIdx.x;

    // gold path score
    float local = 0.0f;
    for (int i = tid; i < SLEN; i += 256) {
        int curt = gold_tags[i];
        int prev = (i == 0) ? STARTT : gold_tags[i - 1];
        local += trans[curt * TT + prev] + feats[i * TT + curt];
    }
    red[tid] = local;
    __syncthreads();
    for (int sft = 128; sft; sft >>= 1) {
        if (tid < sft) red[tid] += red[tid + sft];
        __syncthreads();
    }
    if (tid == 0) gold_s = red[0] + trans[ENDT * TT + gold_tags[SLEN - 1]];
    __syncthreads();
    if (tid >= 64) return;            // wave 0 continues barrier-free

    const int lane = tid;
    const int n = (lane < TT) ? lane : 0;

    float alpha = (lane == STARTT) ? 0.0f : NEGV;
    float cr[TT], cn[TT];
#pragma unroll
    for (int p = 0; p < TT; ++p) cr[p] = cmat[n * TT + p];   // chunk 0 row n

    for (int b = 0; b < NCHUNK; ++b) {
        const float* nxt = cmat + (size_t)((b + 1 < NCHUNK) ? b + 1 : b) * 144u;
#pragma unroll
        for (int p = 0; p < TT; ++p) cn[p] = nxt[n * TT + p]; // prefetch next chunk

        float a[TT];
#pragma unroll
        for (int p = 0; p < TT; ++p) a[p] = __shfl(alpha, p) + cr[p];
        float m = a[0];
#pragma unroll
        for (int p = 1; p < TT; ++p) m = fmaxf(m, a[p]);
        float s = 0.f;
#pragma unroll
        for (int p = 0; p < TT; ++p) s += __expf(a[p] - m);
        float na = m + __logf(s);
        alpha = (lane < TT) ? na : NEGV;
#pragma unroll
        for (int p = 0; p < TT; ++p) cr[p] = cn[p];
    }

    // forward_score = LSE(alpha + trans[END]) ; out = forward - gold
    float v = (lane < TT) ? alpha + trans[ENDT * TT + lane] : -1e30f;
    float mm = v;
#pragma unroll
    for (int off = 32; off; off >>= 1) mm = fmaxf(mm, __shfl_xor(mm, off));
    float ee = (lane < TT) ? __expf(v - mm) : 0.0f;
#pragma unroll
    for (int off = 32; off; off >>= 1) ee += __shfl_xor(ee, off);
    if (lane == 0) out[0] = mm + __logf(ee) - gold_s;
}

// ---------------------------------------------------------------------------
extern "C" void kernel_launch(void* const* d_in, const int* in_sizes, int n_in,
                              void* d_out, int out_size, void* d_ws, size_t ws_size,
                              hipStream_t stream)
{
    const int*   sentence = (const int*)  d_in[0];
    const int*   gold     = (const int*)  d_in[1];
    const float* emb      = (const float*)d_in[2];
    const float* Wih_f    = (const float*)d_in[3];
    const float* Whh_f    = (const float*)d_in[4];
    const float* bih_f    = (const float*)d_in[5];
    const float* bhh_f    = (const float*)d_in[6];
    const float* Wih_b    = (const float*)d_in[7];
    const float* Whh_b    = (const float*)d_in[8];
    const float* bih_b    = (const float*)d_in[9];
    const float* bhh_b    = (const float*)d_in[10];
    const float* h0       = (const float*)d_in[11];
    const float* c0       = (const float*)d_in[12];
    const float* Wtag     = (const float*)d_in[13];
    const float* btag     = (const float*)d_in[14];
    const float* trans    = (const float*)d_in[15];
    float* out = (float*)d_out;
    float* ws  = (float*)d_ws;

    k0_prep  <<<dim3(32, 2),  256, 0, stream>>>(Wih_f, Wih_b, bih_f, bhh_f, bih_b, bhh_b, ws);
    k1_pre   <<<dim3(256, 2), 256, 0, stream>>>(sentence, emb, ws);
    k2_lstm  <<<2,            512, 0, stream>>>(Whh_f, Whh_b, h0, c0, ws);
    k3_feats <<<1024,         256, 0, stream>>>(Wtag, btag, ws);
    k4a_chunk<<<NCHUNK,       192, 0, stream>>>(trans, ws);
    k4b_final<<<1,            256, 0, stream>>>(gold, trans, ws, out);
}